// Round 3
// baseline (691.041 us; speedup 1.0000x reference)
//
#include <hip/hip_runtime.h>

// Problem constants: B=2, S=2048, D=2048, H=16, DH=128
#define B_  2
#define S_  2048
#define D_  2048
#define H_  16
#define DH_ 128
#define M_  (B_ * S_)          // 4096 rows of x / q / k / v (flattened b,s)

typedef __bf16 bf16;
typedef __bf16 bf16x2 __attribute__((ext_vector_type(2)));
typedef __bf16 bf16x4 __attribute__((ext_vector_type(4)));
typedef __bf16 bf16x8 __attribute__((ext_vector_type(8)));
typedef float  f32x4  __attribute__((ext_vector_type(4)));

// 2^x and log2(x) via the raw ISA ops (v_exp_f32 / v_log_f32).
#define EXP2F(x) __builtin_amdgcn_exp2f(x)
#define LOG2F(x) __builtin_amdgcn_logf(x)

// DH^-0.5 * log2(e): fold softmax scale AND the exp->exp2 conversion into Q.
// Scores then live in the log2 domain: sum2 = sum 2^s', lse2 = log2(sum2),
// w = 2^(diag' - lse2).
static constexpr float kQScale = 0.08838834764831845f * 1.4426950408889634f;

__device__ __forceinline__ void async16(const void* g, void* l) {
  __builtin_amdgcn_global_load_lds(
      (const __attribute__((address_space(1))) void*)g,
      (__attribute__((address_space(3))) void*)l, 16, 0, 0);
}

// ---------------------------------------------------------------------------
// fp32 -> bf16 conversion, 4 elems/thread
__global__ void cvt_bf16(const float* __restrict__ s, bf16* __restrict__ d) {
  int i = (blockIdx.x * 256 + threadIdx.x) * 4;
  float4 v = *(const float4*)(s + i);
  bf16x4 o = {(bf16)v.x, (bf16)v.y, (bf16)v.z, (bf16)v.w};
  *(bf16x4*)(d + i) = o;
}

// ---------------------------------------------------------------------------
// GEMM1: C = A(4096x2048) * Bm^T, Bm = concat(Wq,Wk,Wv) (6144x2048).
// Epilogue: RoPE fused for Q,K (f32, via lane-pair shfl), Q scaled by
// kQScale; packed bf16x2 stores. Q,K -> [B,H,S,DH]; V -> [B,S,D].
__global__ __launch_bounds__(256, 2) void gemm_qkv(
    const bf16* __restrict__ A, const bf16* __restrict__ Bm,
    const float* __restrict__ rc, const float* __restrict__ rs,
    bf16* __restrict__ qb, bf16* __restrict__ kb, bf16* __restrict__ vb) {
  __shared__ alignas(16) bf16 As[128 * 32];
  __shared__ alignas(16) bf16 Bs[128 * 32];
  const int tid = threadIdx.x;
  const int lane = tid & 63, wv = tid >> 6;
  const int quad = lane >> 4, c16 = lane & 15;
  const int wm = (wv >> 1) * 64, wn = (wv & 1) * 64;
  const int m0 = blockIdx.y * 128, n0 = blockIdx.x * 128;

  const bf16* ag = A  + (size_t)(m0 + (tid >> 2)) * D_ + (tid & 3) * 8;
  const bf16* bg = Bm + (size_t)(n0 + (tid >> 2)) * D_ + (tid & 3) * 8;
  char* asl = (char*)As + tid * 16;
  char* bsl = (char*)Bs + tid * 16;

  f32x4 acc[4][4] = {};
  for (int k0 = 0; k0 < D_; k0 += 32) {
    __syncthreads();
    async16(ag + k0,            asl);
    async16(ag + k0 + 64 * D_,  asl + 4096);
    async16(bg + k0,            bsl);
    async16(bg + k0 + 64 * D_,  bsl + 4096);
    __syncthreads();
    bf16x8 af[4], bfr[4];
#pragma unroll
    for (int i = 0; i < 4; ++i)
      af[i] = *(const bf16x8*)(As + (wm + i * 16 + c16) * 32 + quad * 8);
#pragma unroll
    for (int j = 0; j < 4; ++j)
      bfr[j] = *(const bf16x8*)(Bs + (wn + j * 16 + c16) * 32 + quad * 8);
#pragma unroll
    for (int i = 0; i < 4; ++i)
#pragma unroll
      for (int j = 0; j < 4; ++j)
        acc[i][j] = __builtin_amdgcn_mfma_f32_16x16x32_bf16(af[i], bfr[j], acc[i][j], 0, 0, 0);
  }

  // ---- epilogue (n0 is block-uniform: region = Q / K / V) ----
  if (n0 < 4096) {                     // Q or K: fused RoPE, packed stores
    bf16* dst = (n0 < 2048) ? qb : kb;
    const float sc = (n0 < 2048) ? kQScale : 1.0f;
#pragma unroll
    for (int i = 0; i < 4; ++i) {
      const int gmi = m0 + wm + i * 16 + quad * 4;
#pragma unroll
      for (int j = 0; j < 4; ++j) {
        const int gn = n0 + wn + j * 16 + c16;
        const int h = (gn >> 7) & 15;
        const int d = gn & 127;
#pragma unroll
        for (int r = 0; r < 4; ++r) {
          float v = acc[i][j][r];
          float p = __shfl_xor(v, 1);          // partner (odd<->even d)
          const int gm = gmi + r;
          const int b = gm >> 11, s = gm & 2047;
          const int si = s * 64 + (d >> 1);
          float c = rc[si], sn = rs[si];
          float re = (v * c - p * sn) * sc;    // valid on even lanes
          float im = (v * sn + p * c) * sc;
          if (!(lane & 1)) {
            bf16x2 o = {(bf16)re, (bf16)im};
            *(bf16x2*)(dst + ((size_t)((b * 16 + h) * 2048 + s) * 128 + d)) = o;
          }
        }
      }
    }
  } else {                             // V: packed bf16x2 stores
#pragma unroll
    for (int i = 0; i < 4; ++i) {
      const int gmi = m0 + wm + i * 16 + quad * 4;
#pragma unroll
      for (int j = 0; j < 4; ++j) {
        const int gn = n0 + wn + j * 16 + c16 - 4096;
#pragma unroll
        for (int r = 0; r < 4; ++r) {
          float v = acc[i][j][r];
          float p = __shfl_xor(v, 1);
          if (!(lane & 1)) {
            bf16x2 o = {(bf16)v, (bf16)p};
            *(bf16x2*)(vb + (size_t)(gmi + r) * 2048 + gn) = o;
          }
        }
      }
    }
  }
}

// ---------------------------------------------------------------------------
// Per (b,h): lse2[s] = log2 sum_k 2^(q'_s . k_k), diag2[s] = q'_s . k_s
// (log2e*scale already folded into q'). Diag extracted only in the n0==m0
// tile (block-uniform). Inner epilogue: exp2 + add only.
__global__ __launch_bounds__(256, 2) void score_lse(
    const bf16* __restrict__ qb, const bf16* __restrict__ kb,
    float* __restrict__ lse, float* __restrict__ diag) {
  __shared__ alignas(16) bf16 Qs[4 * 128 * 32];  // 32KB
  __shared__ alignas(16) bf16 Ks[4 * 128 * 32];  // 32KB
  const int tid = threadIdx.x;
  const int lane = tid & 63, wv = tid >> 6;
  const int quad = lane >> 4, c16 = lane & 15;
  const int wm = wv * 32;                 // each wave owns 32 distinct Q rows
  const int bh = blockIdx.y;
  const int m0 = blockIdx.x * 128;
  const bf16* Q  = qb + (size_t)bh * (S_ * DH_);
  const bf16* Kp = kb + (size_t)bh * (S_ * DH_);

  const bf16* qg = Q + (size_t)(m0 + (tid >> 2)) * DH_ + (tid & 3) * 8;
  char* ql = (char*)Qs + tid * 16;
#pragma unroll
  for (int kt = 0; kt < 4; ++kt) {
    async16(qg + kt * 32,             ql + kt * 8192);
    async16(qg + kt * 32 + 64 * DH_,  ql + kt * 8192 + 4096);
  }

  const bf16* kg = Kp + (size_t)(tid >> 2) * DH_ + (tid & 3) * 8;
  char* kl = (char*)Ks + tid * 16;

  float sums[8] = {0.f, 0.f, 0.f, 0.f, 0.f, 0.f, 0.f, 0.f};

  for (int n0 = 0; n0 < S_; n0 += 128) {
    __syncthreads();
#pragma unroll
    for (int kt = 0; kt < 4; ++kt) {
      async16(kg + (size_t)n0 * DH_ + kt * 32,            kl + kt * 8192);
      async16(kg + (size_t)(n0 + 64) * DH_ + kt * 32,     kl + kt * 8192 + 4096);
    }
    __syncthreads();
    f32x4 acc[2][8] = {};
#pragma unroll
    for (int kt = 0; kt < 4; ++kt) {
      bf16x8 a[2], b[8];
#pragma unroll
      for (int i = 0; i < 2; ++i)
        a[i] = *(const bf16x8*)(Qs + kt * 4096 + (wm + i * 16 + c16) * 32 + quad * 8);
#pragma unroll
      for (int j = 0; j < 8; ++j)
        b[j] = *(const bf16x8*)(Ks + kt * 4096 + (j * 16 + c16) * 32 + quad * 8);
#pragma unroll
      for (int i = 0; i < 2; ++i)
#pragma unroll
        for (int j = 0; j < 8; ++j)
          acc[i][j] = __builtin_amdgcn_mfma_f32_16x16x32_bf16(a[i], b[j], acc[i][j], 0, 0, 0);
    }
    // diagonal tile only (block-uniform branch): diag elem for local row is
    // at j = 2*wv + i, lane predicate c16 == quad*4+r.
    if (n0 == m0) {
#pragma unroll
      for (int i = 0; i < 2; ++i)
#pragma unroll
        for (int r = 0; r < 4; ++r) {
          if (c16 == quad * 4 + r) {
            int row = wm + i * 16 + quad * 4 + r;
            diag[bh * S_ + m0 + row] = acc[i][2 * wv + i][r];
          }
        }
    }
#pragma unroll
    for (int i = 0; i < 2; ++i)
#pragma unroll
      for (int j = 0; j < 8; ++j)
#pragma unroll
        for (int r = 0; r < 4; ++r)
          sums[i * 4 + r] += EXP2F(acc[i][j][r]);
  }

#pragma unroll
  for (int t = 0; t < 8; ++t) {
    float s = sums[t];
    s += __shfl_xor(s, 1);
    s += __shfl_xor(s, 2);
    s += __shfl_xor(s, 4);
    s += __shfl_xor(s, 8);
    if (c16 == 0) {
      int i = t >> 2, r = t & 3;
      lse[bh * S_ + m0 + wm + i * 16 + quad * 4 + r] = LOG2F(s);
    }
  }
}

// ---------------------------------------------------------------------------
// t[b,s,h*128+d] = 2^(diag2 - lse2) * v   (8 bf16 per thread)
__global__ void wv_mul(const bf16* __restrict__ vb, const float* __restrict__ lse,
                       const float* __restrict__ diag, bf16* __restrict__ t) {
  int u = blockIdx.x * 256 + threadIdx.x;   // < 1048576
  int e = u * 8;
  int m = e >> 11;                          // b*2048+s
  int c = e & 2047;                         // h*128+d
  int g = ((m >> 11) * 16 + (c >> 7)) * 2048 + (m & 2047);
  float w = EXP2F(diag[g] - lse[g]);
  bf16x8 v = ((const bf16x8*)vb)[u];
  bf16x8 o;
#pragma unroll
  for (int r = 0; r < 8; ++r) o[r] = (bf16)((float)v[r] * w);
  ((bf16x8*)t)[u] = o;
}

// ---------------------------------------------------------------------------
// GEMM2: out(f32) = t(4096x2048 bf16) * Wo^T(2048x2048 bf16), packed f32x2
// stores via lane-pair shfl.
__global__ __launch_bounds__(256, 2) void gemm_out(
    const bf16* __restrict__ A, const bf16* __restrict__ Bm, float* __restrict__ C) {
  __shared__ alignas(16) bf16 As[128 * 32];
  __shared__ alignas(16) bf16 Bs[128 * 32];
  const int tid = threadIdx.x;
  const int lane = tid & 63, wv = tid >> 6;
  const int quad = lane >> 4, c16 = lane & 15;
  const int wm = (wv >> 1) * 64, wn = (wv & 1) * 64;
  const int m0 = blockIdx.y * 128, n0 = blockIdx.x * 128;

  const bf16* ag = A  + (size_t)(m0 + (tid >> 2)) * D_ + (tid & 3) * 8;
  const bf16* bg = Bm + (size_t)(n0 + (tid >> 2)) * D_ + (tid & 3) * 8;
  char* asl = (char*)As + tid * 16;
  char* bsl = (char*)Bs + tid * 16;

  f32x4 acc[4][4] = {};
  for (int k0 = 0; k0 < D_; k0 += 32) {
    __syncthreads();
    async16(ag + k0,            asl);
    async16(ag + k0 + 64 * D_,  asl + 4096);
    async16(bg + k0,            bsl);
    async16(bg + k0 + 64 * D_,  bsl + 4096);
    __syncthreads();
    bf16x8 af[4], bfr[4];
#pragma unroll
    for (int i = 0; i < 4; ++i)
      af[i] = *(const bf16x8*)(As + (wm + i * 16 + c16) * 32 + quad * 8);
#pragma unroll
    for (int j = 0; j < 4; ++j)
      bfr[j] = *(const bf16x8*)(Bs + (wn + j * 16 + c16) * 32 + quad * 8);
#pragma unroll
    for (int i = 0; i < 4; ++i)
#pragma unroll
      for (int j = 0; j < 4; ++j)
        acc[i][j] = __builtin_amdgcn_mfma_f32_16x16x32_bf16(af[i], bfr[j], acc[i][j], 0, 0, 0);
  }
#pragma unroll
  for (int i = 0; i < 4; ++i)
#pragma unroll
    for (int j = 0; j < 4; ++j)
#pragma unroll
      for (int r = 0; r < 4; ++r) {
        float v = acc[i][j][r];
        float p = __shfl_xor(v, 1);
        if (!(lane & 1)) {
          int gm = m0 + wm + i * 16 + quad * 4 + r;
          int gn = n0 + wn + j * 16 + c16;
          float2 o = {v, p};
          *(float2*)(C + (size_t)gm * D_ + gn) = o;
        }
      }
}

// ---------------------------------------------------------------------------
extern "C" void kernel_launch(void* const* d_in, const int* in_sizes, int n_in,
                              void* d_out, int out_size, void* d_ws, size_t ws_size,
                              hipStream_t stream) {
  (void)in_sizes; (void)n_in; (void)out_size; (void)ws_size;
  const float* x  = (const float*)d_in[0];
  const float* rc = (const float*)d_in[1];
  const float* rs = (const float*)d_in[2];
  const float* Wq = (const float*)d_in[3];
  const float* Wk = (const float*)d_in[4];
  const float* Wv = (const float*)d_in[5];
  const float* Wo = (const float*)d_in[6];

  char* ws = (char*)d_ws;
  bf16* xb   = (bf16*)ws;                          // 8 MB used (x bf16; reused as t)
  bf16* wqkv = (bf16*)(ws + 16777216);             // 24 MB (6144x2048)
  bf16* wob  = (bf16*)(ws + 16777216 + 25165824);  // 8 MB
  bf16* qb   = (bf16*)(ws + 16777216 + 25165824 + 8388608);   // 16 MB
  bf16* kb   = qb + 8388608;                       // 16 MB
  bf16* vb   = kb + 8388608;                       // 16 MB
  float* lse = (float*)(vb + 8388608);             // 256 KB (log2 domain)
  float* dia = lse + 65536;                        // 256 KB (log2 domain)

  cvt_bf16<<<8192, 256, 0, stream>>>(x,  xb);
  cvt_bf16<<<4096, 256, 0, stream>>>(Wq, wqkv);
  cvt_bf16<<<4096, 256, 0, stream>>>(Wk, wqkv + 4194304);
  cvt_bf16<<<4096, 256, 0, stream>>>(Wv, wqkv + 8388608);
  cvt_bf16<<<4096, 256, 0, stream>>>(Wo, wob);

  gemm_qkv<<<dim3(48, 32), 256, 0, stream>>>(xb, wqkv, rc, rs, qb, kb, vb);
  score_lse<<<dim3(16, 32), 256, 0, stream>>>(qb, kb, lse, dia);
  wv_mul<<<4096, 256, 0, stream>>>(vb, lse, dia, xb /* t reuses xb */);
  gemm_out<<<dim3(16, 32), 256, 0, stream>>>(xb, wob, (float*)d_out);
}

// Round 4
// 392.197 us; speedup vs baseline: 1.7620x; 1.7620x over previous
//
#include <hip/hip_runtime.h>

// Problem constants: B=2, S=2048, D=2048, H=16, DH=128
#define B_  2
#define S_  2048
#define D_  2048
#define H_  16
#define DH_ 128
#define M_  (B_ * S_)          // 4096 rows of x / q / k / v (flattened b,s)

typedef __bf16 bf16;
typedef __bf16 bf16x2 __attribute__((ext_vector_type(2)));
typedef __bf16 bf16x4 __attribute__((ext_vector_type(4)));
typedef __bf16 bf16x8 __attribute__((ext_vector_type(8)));
typedef float  f32x4  __attribute__((ext_vector_type(4)));

// 2^x and log2(x) via the raw ISA ops (v_exp_f32 / v_log_f32).
#define EXP2F(x) __builtin_amdgcn_exp2f(x)
#define LOG2F(x) __builtin_amdgcn_logf(x)

// DH^-0.5 * log2(e): fold softmax scale AND the exp->exp2 conversion into Q.
static constexpr float kQScale = 0.08838834764831845f * 1.4426950408889634f;

__device__ __forceinline__ void async16(const void* g, void* l) {
  __builtin_amdgcn_global_load_lds(
      (const __attribute__((address_space(1))) void*)g,
      (__attribute__((address_space(3))) void*)l, 16, 0, 0);
}

// ---------------------------------------------------------------------------
// fp32 -> bf16 conversion, 4 elems/thread
__global__ void cvt_bf16(const float* __restrict__ s, bf16* __restrict__ d) {
  int i = (blockIdx.x * 256 + threadIdx.x) * 4;
  float4 v = *(const float4*)(s + i);
  bf16x4 o = {(bf16)v.x, (bf16)v.y, (bf16)v.z, (bf16)v.w};
  *(bf16x4*)(d + i) = o;
}

// ---------------------------------------------------------------------------
// GEMM1: C = A(4096x2048) * Bm^T, Bm = concat(Wq,Wk,Wv) (6144x2048).
// Epilogue: RoPE fused for Q,K (f32, via lane-pair shfl), Q scaled by
// kQScale; packed bf16x2 stores. Q,K -> [B,H,S,DH]; V -> [B,S,D].
__global__ __launch_bounds__(256, 2) void gemm_qkv(
    const bf16* __restrict__ A, const bf16* __restrict__ Bm,
    const float* __restrict__ rc, const float* __restrict__ rs,
    bf16* __restrict__ qb, bf16* __restrict__ kb, bf16* __restrict__ vb) {
  __shared__ alignas(16) bf16 As[128 * 32];
  __shared__ alignas(16) bf16 Bs[128 * 32];
  const int tid = threadIdx.x;
  const int lane = tid & 63, wv = tid >> 6;
  const int quad = lane >> 4, c16 = lane & 15;
  const int wm = (wv >> 1) * 64, wn = (wv & 1) * 64;
  const int m0 = blockIdx.y * 128, n0 = blockIdx.x * 128;

  const bf16* ag = A  + (size_t)(m0 + (tid >> 2)) * D_ + (tid & 3) * 8;
  const bf16* bg = Bm + (size_t)(n0 + (tid >> 2)) * D_ + (tid & 3) * 8;
  char* asl = (char*)As + tid * 16;
  char* bsl = (char*)Bs + tid * 16;

  f32x4 acc[4][4] = {};
  for (int k0 = 0; k0 < D_; k0 += 32) {
    __syncthreads();
    async16(ag + k0,            asl);
    async16(ag + k0 + 64 * D_,  asl + 4096);
    async16(bg + k0,            bsl);
    async16(bg + k0 + 64 * D_,  bsl + 4096);
    __syncthreads();
    bf16x8 af[4], bfr[4];
#pragma unroll
    for (int i = 0; i < 4; ++i)
      af[i] = *(const bf16x8*)(As + (wm + i * 16 + c16) * 32 + quad * 8);
#pragma unroll
    for (int j = 0; j < 4; ++j)
      bfr[j] = *(const bf16x8*)(Bs + (wn + j * 16 + c16) * 32 + quad * 8);
#pragma unroll
    for (int i = 0; i < 4; ++i)
#pragma unroll
      for (int j = 0; j < 4; ++j)
        acc[i][j] = __builtin_amdgcn_mfma_f32_16x16x32_bf16(af[i], bfr[j], acc[i][j], 0, 0, 0);
  }

  // ---- epilogue (n0 is block-uniform: region = Q / K / V) ----
  if (n0 < 4096) {                     // Q or K: fused RoPE, packed stores
    bf16* dst = (n0 < 2048) ? qb : kb;
    const float sc = (n0 < 2048) ? kQScale : 1.0f;
#pragma unroll
    for (int i = 0; i < 4; ++i) {
      const int gmi = m0 + wm + i * 16 + quad * 4;
#pragma unroll
      for (int j = 0; j < 4; ++j) {
        const int gn = n0 + wn + j * 16 + c16;
        const int h = (gn >> 7) & 15;
        const int d = gn & 127;
#pragma unroll
        for (int r = 0; r < 4; ++r) {
          float v = acc[i][j][r];
          float p = __shfl_xor(v, 1);          // partner (odd<->even d)
          const int gm = gmi + r;
          const int b = gm >> 11, s = gm & 2047;
          const int si = s * 64 + (d >> 1);
          float c = rc[si], sn = rs[si];
          float re = (v * c - p * sn) * sc;    // valid on even lanes
          float im = (v * sn + p * c) * sc;
          if (!(lane & 1)) {
            bf16x2 o = {(bf16)re, (bf16)im};
            *(bf16x2*)(dst + ((size_t)((b * 16 + h) * 2048 + s) * 128 + d)) = o;
          }
        }
      }
    }
  } else {                             // V: packed bf16x2 stores
#pragma unroll
    for (int i = 0; i < 4; ++i) {
      const int gmi = m0 + wm + i * 16 + quad * 4;
#pragma unroll
      for (int j = 0; j < 4; ++j) {
        const int gn = n0 + wn + j * 16 + c16 - 4096;
#pragma unroll
        for (int r = 0; r < 4; ++r) {
          float v = acc[i][j][r];
          float p = __shfl_xor(v, 1);
          if (!(lane & 1)) {
            bf16x2 o = {(bf16)v, (bf16)p};
            *(bf16x2*)(vb + (size_t)(gmi + r) * 2048 + gn) = o;
          }
        }
      }
    }
  }
}

// ---------------------------------------------------------------------------
// Per (b,h): lse2[s] = log2 sum_k 2^(q'_s . k_k), diag2[s] = q'_s . k_s
// (log2e*scale already folded into q'). Diag extracted only in the n0==m0
// tile with STATIC acc indices (dynamic index -> scratch spill, R3 lesson:
// 900 MB WRITE_SIZE, 6x kernel slowdown).
__global__ __launch_bounds__(256, 2) void score_lse(
    const bf16* __restrict__ qb, const bf16* __restrict__ kb,
    float* __restrict__ lse, float* __restrict__ diag) {
  __shared__ alignas(16) bf16 Qs[4 * 128 * 32];  // 32KB
  __shared__ alignas(16) bf16 Ks[4 * 128 * 32];  // 32KB
  const int tid = threadIdx.x;
  const int lane = tid & 63, wv = tid >> 6;
  const int quad = lane >> 4, c16 = lane & 15;
  const int wm = wv * 32;                 // each wave owns 32 distinct Q rows
  const int bh = blockIdx.y;
  const int m0 = blockIdx.x * 128;
  const bf16* Q  = qb + (size_t)bh * (S_ * DH_);
  const bf16* Kp = kb + (size_t)bh * (S_ * DH_);

  const bf16* qg = Q + (size_t)(m0 + (tid >> 2)) * DH_ + (tid & 3) * 8;
  char* ql = (char*)Qs + tid * 16;
#pragma unroll
  for (int kt = 0; kt < 4; ++kt) {
    async16(qg + kt * 32,             ql + kt * 8192);
    async16(qg + kt * 32 + 64 * DH_,  ql + kt * 8192 + 4096);
  }

  const bf16* kg = Kp + (size_t)(tid >> 2) * DH_ + (tid & 3) * 8;
  char* kl = (char*)Ks + tid * 16;

  float sums[8] = {0.f, 0.f, 0.f, 0.f, 0.f, 0.f, 0.f, 0.f};

  for (int n0 = 0; n0 < S_; n0 += 128) {
    __syncthreads();
#pragma unroll
    for (int kt = 0; kt < 4; ++kt) {
      async16(kg + (size_t)n0 * DH_ + kt * 32,            kl + kt * 8192);
      async16(kg + (size_t)(n0 + 64) * DH_ + kt * 32,     kl + kt * 8192 + 4096);
    }
    __syncthreads();
    f32x4 acc[2][8] = {};
#pragma unroll
    for (int kt = 0; kt < 4; ++kt) {
      bf16x8 a[2], b[8];
#pragma unroll
      for (int i = 0; i < 2; ++i)
        a[i] = *(const bf16x8*)(Qs + kt * 4096 + (wm + i * 16 + c16) * 32 + quad * 8);
#pragma unroll
      for (int j = 0; j < 8; ++j)
        b[j] = *(const bf16x8*)(Ks + kt * 4096 + (j * 16 + c16) * 32 + quad * 8);
#pragma unroll
      for (int i = 0; i < 2; ++i)
#pragma unroll
        for (int j = 0; j < 8; ++j)
          acc[i][j] = __builtin_amdgcn_mfma_f32_16x16x32_bf16(a[i], b[j], acc[i][j], 0, 0, 0);
    }
    // Diagonal tile only. All acc indices are compile-time constants;
    // `j == 2*wv + i` is a wave-uniform runtime guard.
    if (n0 == m0) {
#pragma unroll
      for (int i = 0; i < 2; ++i)
#pragma unroll
        for (int j = 0; j < 8; ++j)
          if (j == 2 * wv + i) {
#pragma unroll
            for (int r = 0; r < 4; ++r)
              if (c16 == quad * 4 + r) {
                int row = wm + i * 16 + quad * 4 + r;
                diag[bh * S_ + m0 + row] = acc[i][j][r];
              }
          }
    }
#pragma unroll
    for (int i = 0; i < 2; ++i)
#pragma unroll
      for (int j = 0; j < 8; ++j)
#pragma unroll
        for (int r = 0; r < 4; ++r)
          sums[i * 4 + r] += EXP2F(acc[i][j][r]);
  }

#pragma unroll
  for (int t = 0; t < 8; ++t) {
    float s = sums[t];
    s += __shfl_xor(s, 1);
    s += __shfl_xor(s, 2);
    s += __shfl_xor(s, 4);
    s += __shfl_xor(s, 8);
    if (c16 == 0) {
      int i = t >> 2, r = t & 3;
      lse[bh * S_ + m0 + wm + i * 16 + quad * 4 + r] = LOG2F(s);
    }
  }
}

// ---------------------------------------------------------------------------
// t[b,s,h*128+d] = 2^(diag2 - lse2) * v   (8 bf16 per thread)
__global__ void wv_mul(const bf16* __restrict__ vb, const float* __restrict__ lse,
                       const float* __restrict__ diag, bf16* __restrict__ t) {
  int u = blockIdx.x * 256 + threadIdx.x;   // < 1048576
  int e = u * 8;
  int m = e >> 11;                          // b*2048+s
  int c = e & 2047;                         // h*128+d
  int g = ((m >> 11) * 16 + (c >> 7)) * 2048 + (m & 2047);
  float w = EXP2F(diag[g] - lse[g]);
  bf16x8 v = ((const bf16x8*)vb)[u];
  bf16x8 o;
#pragma unroll
  for (int r = 0; r < 8; ++r) o[r] = (bf16)((float)v[r] * w);
  ((bf16x8*)t)[u] = o;
}

// ---------------------------------------------------------------------------
// GEMM2: out(f32) = t(4096x2048 bf16) * Wo^T(2048x2048 bf16), packed f32x2
// stores via lane-pair shfl.
__global__ __launch_bounds__(256, 2) void gemm_out(
    const bf16* __restrict__ A, const bf16* __restrict__ Bm, float* __restrict__ C) {
  __shared__ alignas(16) bf16 As[128 * 32];
  __shared__ alignas(16) bf16 Bs[128 * 32];
  const int tid = threadIdx.x;
  const int lane = tid & 63, wv = tid >> 6;
  const int quad = lane >> 4, c16 = lane & 15;
  const int wm = (wv >> 1) * 64, wn = (wv & 1) * 64;
  const int m0 = blockIdx.y * 128, n0 = blockIdx.x * 128;

  const bf16* ag = A  + (size_t)(m0 + (tid >> 2)) * D_ + (tid & 3) * 8;
  const bf16* bg = Bm + (size_t)(n0 + (tid >> 2)) * D_ + (tid & 3) * 8;
  char* asl = (char*)As + tid * 16;
  char* bsl = (char*)Bs + tid * 16;

  f32x4 acc[4][4] = {};
  for (int k0 = 0; k0 < D_; k0 += 32) {
    __syncthreads();
    async16(ag + k0,            asl);
    async16(ag + k0 + 64 * D_,  asl + 4096);
    async16(bg + k0,            bsl);
    async16(bg + k0 + 64 * D_,  bsl + 4096);
    __syncthreads();
    bf16x8 af[4], bfr[4];
#pragma unroll
    for (int i = 0; i < 4; ++i)
      af[i] = *(const bf16x8*)(As + (wm + i * 16 + c16) * 32 + quad * 8);
#pragma unroll
    for (int j = 0; j < 4; ++j)
      bfr[j] = *(const bf16x8*)(Bs + (wn + j * 16 + c16) * 32 + quad * 8);
#pragma unroll
    for (int i = 0; i < 4; ++i)
#pragma unroll
      for (int j = 0; j < 4; ++j)
        acc[i][j] = __builtin_amdgcn_mfma_f32_16x16x32_bf16(af[i], bfr[j], acc[i][j], 0, 0, 0);
  }
#pragma unroll
  for (int i = 0; i < 4; ++i)
#pragma unroll
    for (int j = 0; j < 4; ++j)
#pragma unroll
      for (int r = 0; r < 4; ++r) {
        float v = acc[i][j][r];
        float p = __shfl_xor(v, 1);
        if (!(lane & 1)) {
          int gm = m0 + wm + i * 16 + quad * 4 + r;
          int gn = n0 + wn + j * 16 + c16;
          float2 o = {v, p};
          *(float2*)(C + (size_t)gm * D_ + gn) = o;
        }
      }
}

// ---------------------------------------------------------------------------
extern "C" void kernel_launch(void* const* d_in, const int* in_sizes, int n_in,
                              void* d_out, int out_size, void* d_ws, size_t ws_size,
                              hipStream_t stream) {
  (void)in_sizes; (void)n_in; (void)out_size; (void)ws_size;
  const float* x  = (const float*)d_in[0];
  const float* rc = (const float*)d_in[1];
  const float* rs = (const float*)d_in[2];
  const float* Wq = (const float*)d_in[3];
  const float* Wk = (const float*)d_in[4];
  const float* Wv = (const float*)d_in[5];
  const float* Wo = (const float*)d_in[6];

  char* ws = (char*)d_ws;
  bf16* xb   = (bf16*)ws;                          // 8 MB used (x bf16; reused as t)
  bf16* wqkv = (bf16*)(ws + 16777216);             // 24 MB (6144x2048)
  bf16* wob  = (bf16*)(ws + 16777216 + 25165824);  // 8 MB
  bf16* qb   = (bf16*)(ws + 16777216 + 25165824 + 8388608);   // 16 MB
  bf16* kb   = qb + 8388608;                       // 16 MB
  bf16* vb   = kb + 8388608;                       // 16 MB
  float* lse = (float*)(vb + 8388608);             // 256 KB (log2 domain)
  float* dia = lse + 65536;                        // 256 KB (log2 domain)

  cvt_bf16<<<8192, 256, 0, stream>>>(x,  xb);
  cvt_bf16<<<4096, 256, 0, stream>>>(Wq, wqkv);
  cvt_bf16<<<4096, 256, 0, stream>>>(Wk, wqkv + 4194304);
  cvt_bf16<<<4096, 256, 0, stream>>>(Wv, wqkv + 8388608);
  cvt_bf16<<<4096, 256, 0, stream>>>(Wo, wob);

  gemm_qkv<<<dim3(48, 32), 256, 0, stream>>>(xb, wqkv, rc, rs, qb, kb, vb);
  score_lse<<<dim3(16, 32), 256, 0, stream>>>(qb, kb, lse, dia);
  wv_mul<<<4096, 256, 0, stream>>>(vb, lse, dia, xb /* t reuses xb */);
  gemm_out<<<dim3(16, 32), 256, 0, stream>>>(xb, wob, (float*)d_out);
}

// Round 5
// 384.433 us; speedup vs baseline: 1.7976x; 1.0202x over previous
//
#include <hip/hip_runtime.h>

// Problem constants: B=2, S=2048, D=2048, H=16, DH=128
#define B_  2
#define S_  2048
#define D_  2048
#define H_  16
#define DH_ 128
#define NQKV 6144              // Q|K|V concatenated column dim

typedef __bf16 bf16;
typedef __bf16 bf16x2 __attribute__((ext_vector_type(2)));
typedef __bf16 bf16x4 __attribute__((ext_vector_type(4)));
typedef __bf16 bf16x8 __attribute__((ext_vector_type(8)));
typedef float  f32x4  __attribute__((ext_vector_type(4)));

// 2^x and log2(x) via the raw ISA ops (v_exp_f32 / v_log_f32).
#define EXP2F(x) __builtin_amdgcn_exp2f(x)
#define LOG2F(x) __builtin_amdgcn_logf(x)

// DH^-0.5 * log2(e): fold softmax scale AND the exp->exp2 conversion into Q.
static constexpr float kQScale = 0.08838834764831845f * 1.4426950408889634f;

__device__ __forceinline__ void async16(const void* g, void* l) {
  __builtin_amdgcn_global_load_lds(
      (const __attribute__((address_space(1))) void*)g,
      (__attribute__((address_space(3))) void*)l, 16, 0, 0);
}

// ---------------------------------------------------------------------------
// fp32 -> bf16 conversion, 4 elems/thread
__global__ void cvt_bf16(const float* __restrict__ s, bf16* __restrict__ d) {
  int i = (blockIdx.x * 256 + threadIdx.x) * 4;
  float4 v = *(const float4*)(s + i);
  bf16x4 o = {(bf16)v.x, (bf16)v.y, (bf16)v.z, (bf16)v.w};
  *(bf16x4*)(d + i) = o;
}

// ---------------------------------------------------------------------------
// GEMM1: qkv = x(4096x2048) * Wqkv^T (6144x2048), RoPE fused for the Q,K
// column regions (f32 via lane-pair shfl), Q scaled by kQScale. Output is a
// single row-major 4096x6144 bf16 matrix (no scatter).
// BK=64: two 32-K sub-tiles staged per barrier pair (halves barrier drains).
__global__ __launch_bounds__(256, 2) void gemm_qkv(
    const bf16* __restrict__ A, const bf16* __restrict__ Bm,
    const float* __restrict__ rc, const float* __restrict__ rs,
    bf16* __restrict__ C) {
  __shared__ alignas(16) bf16 As[2][128 * 32];   // 16 KB
  __shared__ alignas(16) bf16 Bs[2][128 * 32];   // 16 KB
  const int tid = threadIdx.x;
  const int lane = tid & 63;
  const int wv = tid >> 6;
  const int quad = lane >> 4, c16 = lane & 15;
  const int wm = (wv >> 1) * 64, wn = (wv & 1) * 64;
  const int m0 = blockIdx.y * 128, n0 = blockIdx.x * 128;

  const bf16* ag = A  + (size_t)(m0 + (tid >> 2)) * D_ + (tid & 3) * 8;
  const bf16* bg = Bm + (size_t)(n0 + (tid >> 2)) * D_ + (tid & 3) * 8;
  char* asl = (char*)As + tid * 16;
  char* bsl = (char*)Bs + tid * 16;

  f32x4 acc[4][4] = {};
  for (int k0 = 0; k0 < D_; k0 += 64) {
    __syncthreads();
    async16(ag + k0,                 asl);
    async16(ag + k0 + 64 * D_,       asl + 4096);
    async16(ag + k0 + 32,            asl + 8192);
    async16(ag + k0 + 32 + 64 * D_,  asl + 12288);
    async16(bg + k0,                 bsl);
    async16(bg + k0 + 64 * D_,       bsl + 4096);
    async16(bg + k0 + 32,            bsl + 8192);
    async16(bg + k0 + 32 + 64 * D_,  bsl + 12288);
    __syncthreads();
#pragma unroll
    for (int half = 0; half < 2; ++half) {
      bf16x8 af[4], bfr[4];
#pragma unroll
      for (int i = 0; i < 4; ++i)
        af[i] = *(const bf16x8*)(As[half] + (wm + i * 16 + c16) * 32 + quad * 8);
#pragma unroll
      for (int j = 0; j < 4; ++j)
        bfr[j] = *(const bf16x8*)(Bs[half] + (wn + j * 16 + c16) * 32 + quad * 8);
#pragma unroll
      for (int i = 0; i < 4; ++i)
#pragma unroll
        for (int j = 0; j < 4; ++j)
          acc[i][j] = __builtin_amdgcn_mfma_f32_16x16x32_bf16(af[i], bfr[j], acc[i][j], 0, 0, 0);
    }
  }

  // ---- epilogue (n0 block-uniform: Q / K get RoPE, V passes through) ----
  if (n0 < 4096) {
    const float sc = (n0 < 2048) ? kQScale : 1.0f;
#pragma unroll
    for (int i = 0; i < 4; ++i) {
      const int gmi = m0 + wm + i * 16 + quad * 4;
#pragma unroll
      for (int j = 0; j < 4; ++j) {
        const int gn = n0 + wn + j * 16 + c16;
        const int d = gn & 127;
#pragma unroll
        for (int r = 0; r < 4; ++r) {
          float v = acc[i][j][r];
          float p = __shfl_xor(v, 1);          // partner (odd<->even d)
          const int gm = gmi + r;
          const int s = gm & 2047;
          const int si = s * 64 + (d >> 1);
          float c = rc[si], sn = rs[si];
          float re = (v * c - p * sn) * sc;    // valid on even lanes
          float im = (v * sn + p * c) * sc;
          if (!(lane & 1)) {
            bf16x2 o = {(bf16)re, (bf16)im};
            *(bf16x2*)(C + (size_t)gm * NQKV + gn) = o;
          }
        }
      }
    }
  } else {
#pragma unroll
    for (int i = 0; i < 4; ++i) {
      const int gmi = m0 + wm + i * 16 + quad * 4;
#pragma unroll
      for (int j = 0; j < 4; ++j) {
        const int gn = n0 + wn + j * 16 + c16;
#pragma unroll
        for (int r = 0; r < 4; ++r) {
          float v = acc[i][j][r];
          float p = __shfl_xor(v, 1);
          if (!(lane & 1)) {
            bf16x2 o = {(bf16)v, (bf16)p};
            *(bf16x2*)(C + (size_t)(gmi + r) * NQKV + gn) = o;
          }
        }
      }
    }
  }
}

// ---------------------------------------------------------------------------
// Per (b,h): lse2[s] = log2 sum_k 2^(q'_s . k_k), diag2[s] = q'_s . k_s.
// Q,K read strided from the unified qkv matrix (row stride NQKV).
// Diag extraction uses STATIC acc indices only (R3 lesson: dynamic index ->
// scratch spill, 900 MB WRITE_SIZE).
__global__ __launch_bounds__(256, 2) void score_lse(
    const bf16* __restrict__ qkv,
    float* __restrict__ lse, float* __restrict__ diag) {
  __shared__ alignas(16) bf16 Qs[4 * 128 * 32];  // 32KB
  __shared__ alignas(16) bf16 Ks[4 * 128 * 32];  // 32KB
  const int tid = threadIdx.x;
  const int lane = tid & 63, wv = tid >> 6;
  const int quad = lane >> 4, c16 = lane & 15;
  const int wm = wv * 32;                 // each wave owns 32 distinct Q rows
  const int bh = blockIdx.y;
  const int b = bh >> 4, h = bh & 15;
  const int m0 = blockIdx.x * 128;

  // Q columns [h*128, h*128+128); K columns [2048+h*128, ...)
  const bf16* qg = qkv + (size_t)(b * 2048 + m0 + (tid >> 2)) * NQKV
                 + h * 128 + (tid & 3) * 8;
  char* ql = (char*)Qs + tid * 16;
#pragma unroll
  for (int kt = 0; kt < 4; ++kt) {
    async16(qg + kt * 32,               ql + kt * 8192);
    async16(qg + kt * 32 + (size_t)64 * NQKV, ql + kt * 8192 + 4096);
  }

  const bf16* kg = qkv + (size_t)(b * 2048 + (tid >> 2)) * NQKV
                 + 2048 + h * 128 + (tid & 3) * 8;
  char* kl = (char*)Ks + tid * 16;

  float sums[8] = {0.f, 0.f, 0.f, 0.f, 0.f, 0.f, 0.f, 0.f};

  for (int n0 = 0; n0 < S_; n0 += 128) {
    __syncthreads();
#pragma unroll
    for (int kt = 0; kt < 4; ++kt) {
      async16(kg + (size_t)n0 * NQKV + kt * 32,        kl + kt * 8192);
      async16(kg + (size_t)(n0 + 64) * NQKV + kt * 32, kl + kt * 8192 + 4096);
    }
    __syncthreads();
    f32x4 acc[2][8] = {};
#pragma unroll
    for (int kt = 0; kt < 4; ++kt) {
      bf16x8 a[2], bb[8];
#pragma unroll
      for (int i = 0; i < 2; ++i)
        a[i] = *(const bf16x8*)(Qs + kt * 4096 + (wm + i * 16 + c16) * 32 + quad * 8);
#pragma unroll
      for (int j = 0; j < 8; ++j)
        bb[j] = *(const bf16x8*)(Ks + kt * 4096 + (j * 16 + c16) * 32 + quad * 8);
#pragma unroll
      for (int i = 0; i < 2; ++i)
#pragma unroll
        for (int j = 0; j < 8; ++j)
          acc[i][j] = __builtin_amdgcn_mfma_f32_16x16x32_bf16(a[i], bb[j], acc[i][j], 0, 0, 0);
    }
    // Diagonal tile only; compile-time acc indices, wave-uniform j guard.
    if (n0 == m0) {
#pragma unroll
      for (int i = 0; i < 2; ++i)
#pragma unroll
        for (int j = 0; j < 8; ++j)
          if (j == 2 * wv + i) {
#pragma unroll
            for (int r = 0; r < 4; ++r)
              if (c16 == quad * 4 + r) {
                int row = wm + i * 16 + quad * 4 + r;
                diag[bh * S_ + m0 + row] = acc[i][j][r];
              }
          }
    }
#pragma unroll
    for (int i = 0; i < 2; ++i)
#pragma unroll
      for (int j = 0; j < 8; ++j)
#pragma unroll
        for (int r = 0; r < 4; ++r)
          sums[i * 4 + r] += EXP2F(acc[i][j][r]);
  }

#pragma unroll
  for (int t = 0; t < 8; ++t) {
    float s = sums[t];
    s += __shfl_xor(s, 1);
    s += __shfl_xor(s, 2);
    s += __shfl_xor(s, 4);
    s += __shfl_xor(s, 8);
    if (c16 == 0) {
      int i = t >> 2, r = t & 3;
      lse[bh * S_ + m0 + wm + i * 16 + quad * 4 + r] = LOG2F(s);
    }
  }
}

// ---------------------------------------------------------------------------
// t[b,s,h*128+d] = 2^(diag2 - lse2) * v ; v read from qkv columns 4096..6143.
__global__ void wv_mul(const bf16* __restrict__ qkv, const float* __restrict__ lse,
                       const float* __restrict__ diag, bf16* __restrict__ t) {
  int u = blockIdx.x * 256 + threadIdx.x;   // < 1048576
  int e = u * 8;
  int m = e >> 11;                          // b*2048+s
  int c = e & 2047;                         // h*128+d
  int g = ((m >> 11) * 16 + (c >> 7)) * 2048 + (m & 2047);
  float w = EXP2F(diag[g] - lse[g]);
  bf16x8 v = *(const bf16x8*)(qkv + (size_t)m * NQKV + 4096 + c);
  bf16x8 o;
#pragma unroll
  for (int r = 0; r < 8; ++r) o[r] = (bf16)((float)v[r] * w);
  ((bf16x8*)t)[u] = o;
}

// ---------------------------------------------------------------------------
// GEMM2: out(f32) = t(4096x2048 bf16) * Wo^T(2048x2048 bf16). BK=64, packed
// f32x2 stores via lane-pair shfl.
__global__ __launch_bounds__(256, 2) void gemm_out(
    const bf16* __restrict__ A, const bf16* __restrict__ Bm, float* __restrict__ C) {
  __shared__ alignas(16) bf16 As[2][128 * 32];
  __shared__ alignas(16) bf16 Bs[2][128 * 32];
  const int tid = threadIdx.x;
  const int lane = tid & 63, wv = tid >> 6;
  const int quad = lane >> 4, c16 = lane & 15;
  const int wm = (wv >> 1) * 64, wn = (wv & 1) * 64;
  const int m0 = blockIdx.y * 128, n0 = blockIdx.x * 128;

  const bf16* ag = A  + (size_t)(m0 + (tid >> 2)) * D_ + (tid & 3) * 8;
  const bf16* bg = Bm + (size_t)(n0 + (tid >> 2)) * D_ + (tid & 3) * 8;
  char* asl = (char*)As + tid * 16;
  char* bsl = (char*)Bs + tid * 16;

  f32x4 acc[4][4] = {};
  for (int k0 = 0; k0 < D_; k0 += 64) {
    __syncthreads();
    async16(ag + k0,                 asl);
    async16(ag + k0 + 64 * D_,       asl + 4096);
    async16(ag + k0 + 32,            asl + 8192);
    async16(ag + k0 + 32 + 64 * D_,  asl + 12288);
    async16(bg + k0,                 bsl);
    async16(bg + k0 + 64 * D_,       bsl + 4096);
    async16(bg + k0 + 32,            bsl + 8192);
    async16(bg + k0 + 32 + 64 * D_,  bsl + 12288);
    __syncthreads();
#pragma unroll
    for (int half = 0; half < 2; ++half) {
      bf16x8 af[4], bfr[4];
#pragma unroll
      for (int i = 0; i < 4; ++i)
        af[i] = *(const bf16x8*)(As[half] + (wm + i * 16 + c16) * 32 + quad * 8);
#pragma unroll
      for (int j = 0; j < 4; ++j)
        bfr[j] = *(const bf16x8*)(Bs[half] + (wn + j * 16 + c16) * 32 + quad * 8);
#pragma unroll
      for (int i = 0; i < 4; ++i)
#pragma unroll
        for (int j = 0; j < 4; ++j)
          acc[i][j] = __builtin_amdgcn_mfma_f32_16x16x32_bf16(af[i], bfr[j], acc[i][j], 0, 0, 0);
    }
  }
#pragma unroll
  for (int i = 0; i < 4; ++i)
#pragma unroll
    for (int j = 0; j < 4; ++j)
#pragma unroll
      for (int r = 0; r < 4; ++r) {
        float v = acc[i][j][r];
        float p = __shfl_xor(v, 1);
        if (!(lane & 1)) {
          int gm = m0 + wm + i * 16 + quad * 4 + r;
          int gn = n0 + wn + j * 16 + c16;
          float2 o = {v, p};
          *(float2*)(C + (size_t)gm * D_ + gn) = o;
        }
      }
}

// ---------------------------------------------------------------------------
extern "C" void kernel_launch(void* const* d_in, const int* in_sizes, int n_in,
                              void* d_out, int out_size, void* d_ws, size_t ws_size,
                              hipStream_t stream) {
  (void)in_sizes; (void)n_in; (void)out_size; (void)ws_size;
  const float* x  = (const float*)d_in[0];
  const float* rc = (const float*)d_in[1];
  const float* rs = (const float*)d_in[2];
  const float* Wq = (const float*)d_in[3];
  const float* Wk = (const float*)d_in[4];
  const float* Wv = (const float*)d_in[5];
  const float* Wo = (const float*)d_in[6];

  char* ws = (char*)d_ws;
  bf16* xb   = (bf16*)ws;                          // 16 MB slot (x bf16; reused as t)
  bf16* wqkv = (bf16*)(ws + 16777216);             // 24 MB (6144x2048)
  bf16* wob  = (bf16*)(ws + 16777216 + 25165824);  // 8 MB
  bf16* qkv  = (bf16*)(ws + 16777216 + 25165824 + 8388608);   // 48 MB (4096x6144)
  float* lse = (float*)((char*)qkv + 50331648);    // 256 KB (log2 domain)
  float* dia = lse + 65536;                        // 256 KB (log2 domain)

  cvt_bf16<<<8192, 256, 0, stream>>>(x,  xb);
  cvt_bf16<<<4096, 256, 0, stream>>>(Wq, wqkv);
  cvt_bf16<<<4096, 256, 0, stream>>>(Wk, wqkv + 4194304);
  cvt_bf16<<<4096, 256, 0, stream>>>(Wv, wqkv + 8388608);
  cvt_bf16<<<4096, 256, 0, stream>>>(Wo, wob);

  gemm_qkv<<<dim3(48, 32), 256, 0, stream>>>(xb, wqkv, rc, rs, qkv);
  score_lse<<<dim3(16, 32), 256, 0, stream>>>(qkv, lse, dia);
  wv_mul<<<4096, 256, 0, stream>>>(qkv, lse, dia, xb /* t reuses xb */);
  gemm_out<<<dim3(16, 32), 256, 0, stream>>>(xb, wob, (float*)d_out);
}

// Round 6
// 367.267 us; speedup vs baseline: 1.8816x; 1.0467x over previous
//
#include <hip/hip_runtime.h>

// Problem constants: B=2, S=2048, D=2048, H=16, DH=128
#define B_  2
#define S_  2048
#define D_  2048
#define H_  16
#define DH_ 128
#define NQKV 6144              // Q|K|V concatenated column dim

typedef __bf16 bf16;
typedef __bf16 bf16x2 __attribute__((ext_vector_type(2)));
typedef __bf16 bf16x4 __attribute__((ext_vector_type(4)));
typedef __bf16 bf16x8 __attribute__((ext_vector_type(8)));
typedef float  f32x4  __attribute__((ext_vector_type(4)));

// 2^x and log2(x) via the raw ISA ops (v_exp_f32 / v_log_f32).
#define EXP2F(x) __builtin_amdgcn_exp2f(x)
#define LOG2F(x) __builtin_amdgcn_logf(x)

// DH^-0.5 * log2(e): fold softmax scale AND the exp->exp2 conversion into Q.
static constexpr float kQScale = 0.08838834764831845f * 1.4426950408889634f;

__device__ __forceinline__ void async16(const void* g, void* l) {
  __builtin_amdgcn_global_load_lds(
      (const __attribute__((address_space(1))) void*)g,
      (__attribute__((address_space(3))) void*)l, 16, 0, 0);
}

// ---------------------------------------------------------------------------
// Single fp32 -> bf16 conversion kernel for all 5 tensors (block-uniform
// region select; merging 5 dispatches -> 1 to cut launch overhead).
// Regions (blocks of 1024 elems): x:8192 | Wq:4096 | Wk:4096 | Wv:4096 | Wo:4096
__global__ void cvt_all(const float* __restrict__ x,  const float* __restrict__ wq,
                        const float* __restrict__ wk, const float* __restrict__ wv,
                        const float* __restrict__ wo,
                        bf16* __restrict__ xb, bf16* __restrict__ wqkv,
                        bf16* __restrict__ wob) {
  int bid = blockIdx.x;
  const float* s; bf16* d; int base;
  if (bid < 8192)        { s = x;  d = xb;             base = bid; }
  else if (bid < 12288)  { s = wq; d = wqkv;           base = bid - 8192; }
  else if (bid < 16384)  { s = wk; d = wqkv + 4194304; base = bid - 12288; }
  else if (bid < 20480)  { s = wv; d = wqkv + 8388608; base = bid - 16384; }
  else                   { s = wo; d = wob;            base = bid - 20480; }
  int i = (base * 256 + threadIdx.x) * 4;
  float4 v = *(const float4*)(s + i);
  bf16x4 o = {(bf16)v.x, (bf16)v.y, (bf16)v.z, (bf16)v.w};
  *(bf16x4*)(d + i) = o;
}

// ---------------------------------------------------------------------------
// GEMM1: qkv = x(4096x2048) * Wqkv^T (6144x2048), RoPE fused for the Q,K
// column regions (f32 via lane-pair shfl), Q scaled by kQScale. Output is a
// single row-major 4096x6144 bf16 matrix. BK=64 (two 32-K sub-tiles per
// barrier pair).
__global__ __launch_bounds__(256, 2) void gemm_qkv(
    const bf16* __restrict__ A, const bf16* __restrict__ Bm,
    const float* __restrict__ rc, const float* __restrict__ rs,
    bf16* __restrict__ C) {
  __shared__ alignas(16) bf16 As[2][128 * 32];   // 16 KB
  __shared__ alignas(16) bf16 Bs[2][128 * 32];   // 16 KB
  const int tid = threadIdx.x;
  const int lane = tid & 63;
  const int wv = tid >> 6;
  const int quad = lane >> 4, c16 = lane & 15;
  const int wm = (wv >> 1) * 64, wn = (wv & 1) * 64;
  const int m0 = blockIdx.y * 128, n0 = blockIdx.x * 128;

  const bf16* ag = A  + (size_t)(m0 + (tid >> 2)) * D_ + (tid & 3) * 8;
  const bf16* bg = Bm + (size_t)(n0 + (tid >> 2)) * D_ + (tid & 3) * 8;
  char* asl = (char*)As + tid * 16;
  char* bsl = (char*)Bs + tid * 16;

  f32x4 acc[4][4] = {};
  for (int k0 = 0; k0 < D_; k0 += 64) {
    __syncthreads();
    async16(ag + k0,                 asl);
    async16(ag + k0 + 64 * D_,       asl + 4096);
    async16(ag + k0 + 32,            asl + 8192);
    async16(ag + k0 + 32 + 64 * D_,  asl + 12288);
    async16(bg + k0,                 bsl);
    async16(bg + k0 + 64 * D_,       bsl + 4096);
    async16(bg + k0 + 32,            bsl + 8192);
    async16(bg + k0 + 32 + 64 * D_,  bsl + 12288);
    __syncthreads();
#pragma unroll
    for (int half = 0; half < 2; ++half) {
      bf16x8 af[4], bfr[4];
#pragma unroll
      for (int i = 0; i < 4; ++i)
        af[i] = *(const bf16x8*)(As[half] + (wm + i * 16 + c16) * 32 + quad * 8);
#pragma unroll
      for (int j = 0; j < 4; ++j)
        bfr[j] = *(const bf16x8*)(Bs[half] + (wn + j * 16 + c16) * 32 + quad * 8);
#pragma unroll
      for (int i = 0; i < 4; ++i)
#pragma unroll
        for (int j = 0; j < 4; ++j)
          acc[i][j] = __builtin_amdgcn_mfma_f32_16x16x32_bf16(af[i], bfr[j], acc[i][j], 0, 0, 0);
    }
  }

  // ---- epilogue (n0 block-uniform: Q / K get RoPE, V passes through) ----
  if (n0 < 4096) {
    const float sc = (n0 < 2048) ? kQScale : 1.0f;
#pragma unroll
    for (int i = 0; i < 4; ++i) {
      const int gmi = m0 + wm + i * 16 + quad * 4;
#pragma unroll
      for (int j = 0; j < 4; ++j) {
        const int gn = n0 + wn + j * 16 + c16;
        const int d = gn & 127;
#pragma unroll
        for (int r = 0; r < 4; ++r) {
          float v = acc[i][j][r];
          float p = __shfl_xor(v, 1);          // partner (odd<->even d)
          const int gm = gmi + r;
          const int s = gm & 2047;
          const int si = s * 64 + (d >> 1);
          float c = rc[si], sn = rs[si];
          float re = (v * c - p * sn) * sc;    // valid on even lanes
          float im = (v * sn + p * c) * sc;
          if (!(lane & 1)) {
            bf16x2 o = {(bf16)re, (bf16)im};
            *(bf16x2*)(C + (size_t)gm * NQKV + gn) = o;
          }
        }
      }
    }
  } else {
#pragma unroll
    for (int i = 0; i < 4; ++i) {
      const int gmi = m0 + wm + i * 16 + quad * 4;
#pragma unroll
      for (int j = 0; j < 4; ++j) {
        const int gn = n0 + wn + j * 16 + c16;
#pragma unroll
        for (int r = 0; r < 4; ++r) {
          float v = acc[i][j][r];
          float p = __shfl_xor(v, 1);
          if (!(lane & 1)) {
            bf16x2 o = {(bf16)v, (bf16)p};
            *(bf16x2*)(C + (size_t)(gmi + r) * NQKV + gn) = o;
          }
        }
      }
    }
  }
}

// ---------------------------------------------------------------------------
// Fused per-(b,h) score + weight + V-scale kernel:
//   lse2[s] = log2 sum_k 2^(q'_s . k_k), diag2[s] = q'_s . k_s  (LDS only)
//   t[b,s,h*128+d] = 2^(diag2-lse2) * V[b,s,h*128+d]
// Q,K,V read strided from unified qkv (row stride NQKV). Diag extraction
// uses STATIC acc indices only (R3 lesson: dynamic index -> scratch spill).
__global__ __launch_bounds__(256, 2) void score_wv(
    const bf16* __restrict__ qkv, bf16* __restrict__ t) {
  __shared__ alignas(16) bf16 Qs[4 * 128 * 32];  // 32KB
  __shared__ alignas(16) bf16 Ks[4 * 128 * 32];  // 32KB
  __shared__ float diagL[128];
  __shared__ float lseL[128];
  const int tid = threadIdx.x;
  const int lane = tid & 63, wv = tid >> 6;
  const int quad = lane >> 4, c16 = lane & 15;
  const int wm = wv * 32;                 // each wave owns 32 distinct Q rows
  const int bh = blockIdx.y;
  const int b = bh >> 4, h = bh & 15;
  const int m0 = blockIdx.x * 128;

  // Q columns [h*128, h*128+128); K columns [2048+h*128, ...)
  const bf16* qg = qkv + (size_t)(b * 2048 + m0 + (tid >> 2)) * NQKV
                 + h * 128 + (tid & 3) * 8;
  char* ql = (char*)Qs + tid * 16;
#pragma unroll
  for (int kt = 0; kt < 4; ++kt) {
    async16(qg + kt * 32,                     ql + kt * 8192);
    async16(qg + kt * 32 + (size_t)64 * NQKV, ql + kt * 8192 + 4096);
  }

  const bf16* kg = qkv + (size_t)(b * 2048 + (tid >> 2)) * NQKV
                 + 2048 + h * 128 + (tid & 3) * 8;
  char* kl = (char*)Ks + tid * 16;

  float sums[8] = {0.f, 0.f, 0.f, 0.f, 0.f, 0.f, 0.f, 0.f};

  for (int n0 = 0; n0 < S_; n0 += 128) {
    __syncthreads();
#pragma unroll
    for (int kt = 0; kt < 4; ++kt) {
      async16(kg + (size_t)n0 * NQKV + kt * 32,        kl + kt * 8192);
      async16(kg + (size_t)(n0 + 64) * NQKV + kt * 32, kl + kt * 8192 + 4096);
    }
    __syncthreads();
    f32x4 acc[2][8] = {};
#pragma unroll
    for (int kt = 0; kt < 4; ++kt) {
      bf16x8 a[2], bb[8];
#pragma unroll
      for (int i = 0; i < 2; ++i)
        a[i] = *(const bf16x8*)(Qs + kt * 4096 + (wm + i * 16 + c16) * 32 + quad * 8);
#pragma unroll
      for (int j = 0; j < 8; ++j)
        bb[j] = *(const bf16x8*)(Ks + kt * 4096 + (j * 16 + c16) * 32 + quad * 8);
#pragma unroll
      for (int i = 0; i < 2; ++i)
#pragma unroll
        for (int j = 0; j < 8; ++j)
          acc[i][j] = __builtin_amdgcn_mfma_f32_16x16x32_bf16(a[i], bb[j], acc[i][j], 0, 0, 0);
    }
    // Diagonal tile only; compile-time acc indices, wave-uniform j guard.
    if (n0 == m0) {
#pragma unroll
      for (int i = 0; i < 2; ++i)
#pragma unroll
        for (int j = 0; j < 8; ++j)
          if (j == 2 * wv + i) {
#pragma unroll
            for (int r = 0; r < 4; ++r)
              if (c16 == quad * 4 + r)
                diagL[wm + i * 16 + quad * 4 + r] = acc[i][j][r];
          }
    }
#pragma unroll
    for (int i = 0; i < 2; ++i)
#pragma unroll
      for (int j = 0; j < 8; ++j)
#pragma unroll
        for (int r = 0; r < 4; ++r)
          sums[i * 4 + r] += EXP2F(acc[i][j][r]);
  }

#pragma unroll
  for (int tix = 0; tix < 8; ++tix) {
    float s = sums[tix];
    s += __shfl_xor(s, 1);
    s += __shfl_xor(s, 2);
    s += __shfl_xor(s, 4);
    s += __shfl_xor(s, 8);
    if (c16 == 0) {
      int i = tix >> 2, r = tix & 3;
      lseL[wm + i * 16 + quad * 4 + r] = LOG2F(s);
    }
  }

  // ---- fused V scale: t = 2^(diag - lse) * V for this block's 128 rows ----
  __syncthreads();                       // diagL/lseL visible
  const int row = tid >> 1, ch = tid & 1;
  const float w = EXP2F(diagL[row] - lseL[row]);
  const size_t grow = (size_t)(b * 2048 + m0 + row);
  const bf16* vsrc = qkv + grow * NQKV + 4096 + h * 128 + ch * 64;
  bf16* tdst = t + grow * 2048 + h * 128 + ch * 64;
#pragma unroll
  for (int c = 0; c < 8; ++c) {
    bf16x8 vv = *(const bf16x8*)(vsrc + c * 8);
    bf16x8 oo;
#pragma unroll
    for (int r = 0; r < 8; ++r) oo[r] = (bf16)((float)vv[r] * w);
    *(bf16x8*)(tdst + c * 8) = oo;
  }
}

// ---------------------------------------------------------------------------
// GEMM2: out(f32) = t(4096x2048 bf16) * Wo^T(2048x2048 bf16). BK=64, packed
// f32x2 stores via lane-pair shfl.
__global__ __launch_bounds__(256, 2) void gemm_out(
    const bf16* __restrict__ A, const bf16* __restrict__ Bm, float* __restrict__ C) {
  __shared__ alignas(16) bf16 As[2][128 * 32];
  __shared__ alignas(16) bf16 Bs[2][128 * 32];
  const int tid = threadIdx.x;
  const int lane = tid & 63, wv = tid >> 6;
  const int quad = lane >> 4, c16 = lane & 15;
  const int wm = (wv >> 1) * 64, wn = (wv & 1) * 64;
  const int m0 = blockIdx.y * 128, n0 = blockIdx.x * 128;

  const bf16* ag = A  + (size_t)(m0 + (tid >> 2)) * D_ + (tid & 3) * 8;
  const bf16* bg = Bm + (size_t)(n0 + (tid >> 2)) * D_ + (tid & 3) * 8;
  char* asl = (char*)As + tid * 16;
  char* bsl = (char*)Bs + tid * 16;

  f32x4 acc[4][4] = {};
  for (int k0 = 0; k0 < D_; k0 += 64) {
    __syncthreads();
    async16(ag + k0,                 asl);
    async16(ag + k0 + 64 * D_,       asl + 4096);
    async16(ag + k0 + 32,            asl + 8192);
    async16(ag + k0 + 32 + 64 * D_,  asl + 12288);
    async16(bg + k0,                 bsl);
    async16(bg + k0 + 64 * D_,       bsl + 4096);
    async16(bg + k0 + 32,            bsl + 8192);
    async16(bg + k0 + 32 + 64 * D_,  bsl + 12288);
    __syncthreads();
#pragma unroll
    for (int half = 0; half < 2; ++half) {
      bf16x8 af[4], bfr[4];
#pragma unroll
      for (int i = 0; i < 4; ++i)
        af[i] = *(const bf16x8*)(As[half] + (wm + i * 16 + c16) * 32 + quad * 8);
#pragma unroll
      for (int j = 0; j < 4; ++j)
        bfr[j] = *(const bf16x8*)(Bs[half] + (wn + j * 16 + c16) * 32 + quad * 8);
#pragma unroll
      for (int i = 0; i < 4; ++i)
#pragma unroll
        for (int j = 0; j < 4; ++j)
          acc[i][j] = __builtin_amdgcn_mfma_f32_16x16x32_bf16(af[i], bfr[j], acc[i][j], 0, 0, 0);
    }
  }
#pragma unroll
  for (int i = 0; i < 4; ++i)
#pragma unroll
    for (int j = 0; j < 4; ++j)
#pragma unroll
      for (int r = 0; r < 4; ++r) {
        float v = acc[i][j][r];
        float p = __shfl_xor(v, 1);
        if (!(lane & 1)) {
          int gm = m0 + wm + i * 16 + quad * 4 + r;
          int gn = n0 + wn + j * 16 + c16;
          float2 o = {v, p};
          *(float2*)(C + (size_t)gm * D_ + gn) = o;
        }
      }
}

// ---------------------------------------------------------------------------
extern "C" void kernel_launch(void* const* d_in, const int* in_sizes, int n_in,
                              void* d_out, int out_size, void* d_ws, size_t ws_size,
                              hipStream_t stream) {
  (void)in_sizes; (void)n_in; (void)out_size; (void)ws_size;
  const float* x  = (const float*)d_in[0];
  const float* rc = (const float*)d_in[1];
  const float* rs = (const float*)d_in[2];
  const float* Wq = (const float*)d_in[3];
  const float* Wk = (const float*)d_in[4];
  const float* Wv = (const float*)d_in[5];
  const float* Wo = (const float*)d_in[6];

  char* ws = (char*)d_ws;
  bf16* xb   = (bf16*)ws;                          // 16 MB slot (x bf16; reused as t)
  bf16* wqkv = (bf16*)(ws + 16777216);             // 24 MB (6144x2048)
  bf16* wob  = (bf16*)(ws + 16777216 + 25165824);  // 8 MB
  bf16* qkv  = (bf16*)(ws + 16777216 + 25165824 + 8388608);   // 48 MB (4096x6144)

  cvt_all<<<24576, 256, 0, stream>>>(x, Wq, Wk, Wv, Wo, xb, wqkv, wob);
  gemm_qkv<<<dim3(48, 32), 256, 0, stream>>>(xb, wqkv, rc, rs, qkv);
  score_wv<<<dim3(16, 32), 256, 0, stream>>>(qkv, xb /* t reuses xb */);
  gemm_out<<<dim3(16, 32), 256, 0, stream>>>(xb, wob, (float*)d_out);
}